// Round 1
// baseline (436.195 us; speedup 1.0000x reference)
//
#include <hip/hip_runtime.h>
#include <hip/hip_bf16.h>
#include <cstdint>

// Problem constants
#define BATCH 32
#define CIN   256
#define COUT  256
#define HW    56
#define NEXP  8
#define HP    58           // padded spatial
#define KTOT  2304         // CIN*9

typedef __bf16 bf16x8 __attribute__((ext_vector_type(8)));
typedef float  f32x4  __attribute__((ext_vector_type(4)));
typedef unsigned short u16x8 __attribute__((ext_vector_type(8)));

static __device__ __forceinline__ unsigned short f32_to_bf16(float f) {
    uint32_t u = __builtin_bit_cast(uint32_t, f);
    return (unsigned short)((u + 0x7FFFu + ((u >> 16) & 1u)) >> 16);
}

// ---------------- GAP: gap[b][c] = mean over 56x56 ----------------
__global__ void gap_kernel(const float* __restrict__ x, float* __restrict__ gap) {
    int c = blockIdx.x, b = blockIdx.y;
    const float* p = x + ((size_t)(b * CIN + c)) * (HW * HW);
    int t = threadIdx.x;
    float s = 0.f;
    for (int j = t; j < 784; j += 256) {               // 3136/4 float4s
        float4 v = reinterpret_cast<const float4*>(p)[j];
        s += v.x + v.y + v.z + v.w;
    }
    #pragma unroll
    for (int off = 32; off; off >>= 1) s += __shfl_down(s, off, 64);
    __shared__ float partial[4];
    if ((t & 63) == 0) partial[t >> 6] = s;
    __syncthreads();
    if (t == 0)
        gap[b * CIN + c] = (partial[0] + partial[1] + partial[2] + partial[3]) * (1.0f / 3136.0f);
}

// ---------------- routing[b][e] = sigmoid(gap[b]·fc_w[e] + fc_b[e]) ----------------
__global__ void routing_kernel(const float* __restrict__ gap, const float* __restrict__ fcw,
                               const float* __restrict__ fcb, float* __restrict__ rout) {
    int t = threadIdx.x;           // 256 threads: (b,e)
    int b = t >> 3, e = t & 7;
    const float* g = gap + b * CIN;
    const float* w = fcw + e * CIN;
    float z = fcb[e];
    for (int c = 0; c < CIN; ++c) z += g[c] * w[c];
    rout[b * NEXP + e] = 1.f / (1.f + expf(-z));
}

// ---------------- x fp32 [b][i][56][56] -> xTp bf16 [b][58][58][i] (zero halo) ----------------
__global__ void transpose_kernel(const float* __restrict__ x, unsigned short* __restrict__ xtp) {
    int hp = blockIdx.x;           // 0..57 padded row
    int ib = blockIdx.y;           // i-block of 32
    int b  = blockIdx.z;
    int t  = threadIdx.x;
    __shared__ float tile[32][57];
    bool in_h = (hp >= 1 && hp <= HW);
    if (in_h) {
        const float* src = x + (((size_t)b * CIN + ib * 32) * HW + (hp - 1)) * HW;
        for (int idx = t; idx < 32 * HW; idx += 256) {
            int il = idx / HW, w = idx - il * HW;
            tile[il][w] = src[(size_t)il * (HW * HW) + w];
        }
    }
    __syncthreads();
    unsigned short* dst = xtp + (((size_t)b * HP + hp) * HP) * CIN + ib * 32;
    for (int idx = t; idx < HP * 32; idx += 256) {
        int wp = idx >> 5, il = idx & 31;
        float v = 0.f;
        if (in_h && wp >= 1 && wp <= HW) v = tile[il][wp - 1];
        dst[(size_t)wp * CIN + il] = f32_to_bf16(v);
    }
}

// ---------------- cmb[b][o][r][i] = sum_e rout[b][e] * kw[e][o][i][r]  (bf16) ----------------
__global__ void combine_kernel(const float* __restrict__ kw, const float* __restrict__ rout,
                               unsigned short* __restrict__ cmb) {
    int o = blockIdx.x;
    int t = threadIdx.x;
    __shared__ float rs[BATCH][NEXP];
    rs[t >> 3][t & 7] = rout[t];
    __syncthreads();
    for (int r = 0; r < 9; ++r) {
        int i = t;
        float kv[NEXP];
        #pragma unroll
        for (int e = 0; e < NEXP; ++e)
            kv[e] = kw[(((size_t)e * COUT + o) * CIN + i) * 9 + r];
        for (int b = 0; b < BATCH; ++b) {
            float s = 0.f;
            #pragma unroll
            for (int e = 0; e < NEXP; ++e) s += rs[b][e] * kv[e];
            cmb[(((size_t)b * COUT + o) * 9 + r) * CIN + i] = f32_to_bf16(s);
        }
    }
}

// ---------------- conv: implicit GEMM, BM=128 (o) x BN=112 pixels (14x8), K=2304 ----------------
// LDS: A tile [128 rows][64B data + 16B pad]  = 10240 B
//      X window [16x10 pos][64B data + 16B pad] = 12800 B
#define WIN_OFF 10240

__global__ __launch_bounds__(256)
void conv_kernel(const unsigned short* __restrict__ xtp, const unsigned short* __restrict__ cmb,
                 float* __restrict__ out) {
    __shared__ __align__(16) char lds[23040];
    int t = threadIdx.x;
    int wave = t >> 6, l = t & 63, lr = l & 15, lk = l >> 4;
    int b = blockIdx.z;
    int o0 = blockIdx.y * 128;
    int pt = blockIdx.x;                  // 0..27 : 4 (ty) x 7 (tx)
    int ty = pt / 7, tx = pt - ty * 7;
    int oh0 = ty * 14, ow0 = tx * 8;

    const unsigned short* xb = xtp + (size_t)b * (HP * HP * CIN);
    const unsigned short* cb = cmb + ((size_t)b * COUT + o0) * KTOT;

    f32x4 acc[2][7];
    #pragma unroll
    for (int mi = 0; mi < 2; ++mi)
        #pragma unroll
        for (int nt = 0; nt < 7; ++nt) acc[mi][nt] = (f32x4){0.f, 0.f, 0.f, 0.f};

    for (int ib = 0; ib < 8; ++ib) {
        #pragma unroll
        for (int r = 0; r < 9; ++r) {
            __syncthreads();
            if (r == 0) {
                // stage input window: 16x10 positions x 32 i  (640 x 16B chunks)
                for (int c = t; c < 640; c += 256) {
                    int pos = c >> 2, q = c & 3;
                    int hh = pos / 10, ww = pos - hh * 10;
                    const unsigned short* src =
                        xb + ((size_t)(oh0 + hh) * HP + (ow0 + ww)) * CIN + ib * 32 + q * 8;
                    u16x8 v = *reinterpret_cast<const u16x8*>(src);
                    *reinterpret_cast<u16x8*>(&lds[WIN_OFF + pos * 80 + q * 16]) = v;
                }
            }
            // stage A tile: 128 o-rows x 32 i (512 x 16B chunks)
            for (int c = t; c < 512; c += 256) {
                int row = c >> 2, q = c & 3;
                const unsigned short* src =
                    cb + (size_t)row * KTOT + r * CIN + ib * 32 + q * 8;
                u16x8 v = *reinterpret_cast<const u16x8*>(src);
                *reinterpret_cast<u16x8*>(&lds[row * 80 + q * 16]) = v;
            }
            __syncthreads();
            const int dh = r / 3, dw = r - (r / 3) * 3;
            bf16x8 af[2];
            #pragma unroll
            for (int mi = 0; mi < 2; ++mi)
                af[mi] = *reinterpret_cast<const bf16x8*>(
                    &lds[(wave * 32 + mi * 16 + lr) * 80 + lk * 16]);
            #pragma unroll
            for (int nt = 0; nt < 7; ++nt) {
                int ph = nt * 2 + (lr >> 3) + dh;
                int pw = (lr & 7) + dw;
                bf16x8 bfr = *reinterpret_cast<const bf16x8*>(
                    &lds[WIN_OFF + (ph * 10 + pw) * 80 + lk * 16]);
                #pragma unroll
                for (int mi = 0; mi < 2; ++mi)
                    acc[mi][nt] = __builtin_amdgcn_mfma_f32_16x16x32_bf16(af[mi], bfr, acc[mi][nt], 0, 0, 0);
            }
        }
    }
    // epilogue: D col = lane&15 (pixel), row = (lane>>4)*4 + reg (o)
    #pragma unroll
    for (int mi = 0; mi < 2; ++mi) {
        #pragma unroll
        for (int nt = 0; nt < 7; ++nt) {
            int ph = nt * 2 + (lr >> 3), pw = lr & 7;
            #pragma unroll
            for (int reg = 0; reg < 4; ++reg) {
                int o = o0 + wave * 32 + mi * 16 + lk * 4 + reg;
                out[(((size_t)b * COUT + o) * HW + (oh0 + ph)) * HW + (ow0 + pw)] = acc[mi][nt][reg];
            }
        }
    }
}

extern "C" void kernel_launch(void* const* d_in, const int* in_sizes, int n_in,
                              void* d_out, int out_size, void* d_ws, size_t ws_size,
                              hipStream_t stream) {
    const float* x   = (const float*)d_in[0];
    const float* kw  = (const float*)d_in[1];
    const float* fcw = (const float*)d_in[2];
    const float* fcb = (const float*)d_in[3];
    float* out = (float*)d_out;

    // workspace layout (bytes, 256-aligned)
    char* ws = (char*)d_ws;
    float* gap  = (float*)(ws + 0);                        //  32768 B
    float* rout = (float*)(ws + 32768);                    //   1024 B
    unsigned short* cmb = (unsigned short*)(ws + 33792);   // 37748736 B
    unsigned short* xtp = (unsigned short*)(ws + 33792 + 37748736); // 55107584 B
    // total ~92.9 MB

    gap_kernel<<<dim3(CIN, BATCH), 256, 0, stream>>>(x, gap);
    routing_kernel<<<1, 256, 0, stream>>>(gap, fcw, fcb, rout);
    transpose_kernel<<<dim3(HP, 8, BATCH), 256, 0, stream>>>(x, xtp);
    combine_kernel<<<COUT, 256, 0, stream>>>(kw, rout, cmb);
    conv_kernel<<<dim3(28, 2, BATCH), 256, 0, stream>>>(xtp, cmb, out);
}